// Round 14
// baseline (194.551 us; speedup 1.0000x reference)
//
#include <hip/hip_runtime.h>
#include <hip/hip_bf16.h>
#include <hip/hip_fp8.h>

#define NTOK 100000
#define EPS 1e-5f

using frag  = __attribute__((ext_vector_type(8))) short;  // 8 bf16 (4 VGPR)
using f32x4 = __attribute__((ext_vector_type(4))) float;
typedef __hip_bfloat16 bf16;
typedef unsigned short ushort_t;

__device__ inline float bits2f(unsigned int u) { union { unsigned int i; float f; } x; x.i = u; return x.f; }
__device__ inline void bfu_unpack(unsigned int u, float& lo, float& hi) {
  lo = bits2f(u << 16);
  hi = bits2f(u & 0xffff0000u);
}
__device__ inline short f2bf_s(float x) { bf16 t = __float2bfloat16(x); return *(short*)&t; }

// fp8 e4m3 <-> f32 via gfx950 HW converts (SW fallback guarded)
__device__ inline float4 fp8x4_to_f4(unsigned int u) {
#if __has_builtin(__builtin_amdgcn_cvt_pk_f32_fp8)
  auto lo = __builtin_amdgcn_cvt_pk_f32_fp8(u, false);  // bytes 0,1
  auto hi = __builtin_amdgcn_cvt_pk_f32_fp8(u, true);   // bytes 2,3
  return make_float4(lo[0], lo[1], hi[0], hi[1]);
#else
  __hip_fp8_e4m3 a, b, c, d;
  a.__x = u & 0xff; b.__x = (u >> 8) & 0xff; c.__x = (u >> 16) & 0xff; d.__x = (u >> 24) & 0xff;
  return make_float4((float)a, (float)b, (float)c, (float)d);
#endif
}
__device__ inline unsigned char f_to_fp8(float f) {
#if __has_builtin(__builtin_amdgcn_cvt_pk_fp8_f32)
  return (unsigned char)(__builtin_amdgcn_cvt_pk_fp8_f32(f, f, 0, false) & 0xff);
#else
  __hip_fp8_e4m3 t(f); return t.__x;
#endif
}
// 8 fp8 (uint2) -> bf16 MFMA A-frag; exact re-encode (e4m3 subset of bf16)
__device__ inline frag fp8x8_to_bf16frag(uint2 u) {
  float4 a = fp8x4_to_f4(u.x);
  float4 b = fp8x4_to_f4(u.y);
  frag f;
  f[0] = f2bf_s(a.x); f[1] = f2bf_s(a.y); f[2] = f2bf_s(a.z); f[3] = f2bf_s(a.w);
  f[4] = f2bf_s(b.x); f[5] = f2bf_s(b.y); f[6] = f2bf_s(b.z); f[7] = f2bf_s(b.w);
  return f;
}

// async global->LDS, 16B per lane; zero VGPR staging cost.
#define GL_LDS16(gsrc, ldst)                                                  \
  __builtin_amdgcn_global_load_lds(                                           \
      (const __attribute__((address_space(1))) void*)(gsrc),                  \
      (__attribute__((address_space(3))) void*)(ldst), 16, 0, 0)

// ---------------------------------------------------------------------------
// fp32 -> bf16 conversions
// ---------------------------------------------------------------------------
__global__ __launch_bounds__(256) void cvt_x_kernel(const float* __restrict__ in,
                                                    bf16* __restrict__ out) {
  const int e = (blockIdx.x * 256 + threadIdx.x) * 4;
  float4 v = *(const float4*)&in[e];
  bf16 o[4] = {__float2bfloat16(v.x), __float2bfloat16(v.y),
               __float2bfloat16(v.z), __float2bfloat16(v.w)};
  *(ulong1*)&out[e] = *(ulong1*)o;
}

__global__ __launch_bounds__(256) void cvt_w_kernel(
    const float* __restrict__ w0, const float* __restrict__ w1,
    const float* __restrict__ w2, const float* __restrict__ w3,
    bf16* __restrict__ out) {
  const int e = (blockIdx.x * 256 + threadIdx.x) * 4;
  const float* src;
  int off;
  if (e < 49152)       { src = w0; off = 0; }
  else if (e < 65536)  { src = w1; off = 49152; }
  else if (e < 131072) { src = w2; off = 65536; }
  else                 { src = w3; off = 131072; }
  float4 v = *(const float4*)&src[e - off];
  bf16 o[4] = {__float2bfloat16(v.x), __float2bfloat16(v.y),
               __float2bfloat16(v.z), __float2bfloat16(v.w)};
  *(ulong1*)&out[e] = *(ulong1*)o;
}

// ---------------------------------------------------------------------------
// B staging via global_load_lds (512-thread block): slot g = r*512+tid
// (row=g>>4, u=g&15), byte offset g*16 -- LINEAR in lane. Swizzle in the
// per-lane GLOBAL address: unit u^(row&15). Frag read: unit (kc*4+kg)^lr
// (measured 0 bank conflicts).
// ---------------------------------------------------------------------------
__device__ __forceinline__ void stage_B(const bf16* __restrict__ Wslab, int KTOT,
                                        ushort_t* Bs, int tid) {
#pragma unroll
  for (int r = 0; r < 4; ++r) {
    const int g = r * 512 + tid, row = g >> 4, u = g & 15;
    GL_LDS16(Wslab + (size_t)row * KTOT + (u ^ (row & 15)) * 8, Bs + g * 8);
  }
}

// 64 MFMAs over one staged 128x128 B chunk with preloaded A frags
__device__ __forceinline__ void mfma_step(const frag (&a)[2][4], ushort_t* Bs,
                                          int lr, int kg, f32x4 (&acc)[2][8]) {
#pragma unroll
  for (int kc = 0; kc < 4; ++kc) {
    const int uoff = ((kc * 4 + kg) ^ lr) * 8;
#pragma unroll
    for (int j = 0; j < 8; ++j) {
      frag b = *(const frag*)&Bs[(lr + 16 * j) * 128 + uoff];
      acc[0][j] = __builtin_amdgcn_mfma_f32_16x16x32_bf16(a[0][kc], b, acc[0][j], 0, 0, 0);
      acc[1][j] = __builtin_amdgcn_mfma_f32_16x16x32_bf16(a[1][kc], b, acc[1][j], 0, 0, 0);
    }
  }
}

// ---------------------------------------------------------------------------
// QKV projection (K=128): 8 waves x 32 rows = 256-row block.
// blockIdx.y 0 -> q (bf16), 1 -> k (fp8), 2 -> v (fp8)
// ---------------------------------------------------------------------------
__global__ __launch_bounds__(512, 4) void k_qkv(
    const bf16* __restrict__ A, const bf16* __restrict__ W,
    const float* __restrict__ bias, bf16* __restrict__ qout,
    unsigned char* __restrict__ kout, unsigned char* __restrict__ vout, int M) {
  __shared__ ushort_t Bs[16384];
  const int tid = threadIdx.x;
  const int lane = tid & 63;
  const int wid = tid >> 6;
  const int row0 = blockIdx.x * 256 + wid * 32;
  const int cbase = blockIdx.y * 128;
  const int lr = lane & 15, kg = lane >> 4;

  int r0 = row0 + lr;      if (r0 > M - 1) r0 = M - 1;
  int r1 = row0 + 16 + lr; if (r1 > M - 1) r1 = M - 1;
  frag a[2][4];
#pragma unroll
  for (int kc = 0; kc < 4; ++kc) {
    a[0][kc] = *(const frag*)(A + (size_t)r0 * 128 + kg * 8 + kc * 32);
    a[1][kc] = *(const frag*)(A + (size_t)r1 * 128 + kg * 8 + kc * 32);
  }
  stage_B(W + (size_t)cbase * 128, 128, Bs, tid);
  __syncthreads();  // drains vmcnt(0): B in LDS, A in regs

  f32x4 acc[2][8] = {};
  mfma_step(a, Bs, lr, kg, acc);

  float bs[8];
#pragma unroll
  for (int j = 0; j < 8; ++j) bs[j] = bias[cbase + lr + 16 * j];
  const int y = blockIdx.y;
  unsigned char* f8dst = (y == 1) ? kout : vout;
#pragma unroll
  for (int i = 0; i < 2; ++i)
#pragma unroll
    for (int r = 0; r < 4; ++r) {
      const int row = row0 + 16 * i + 4 * kg + r;
      if (row >= M) continue;
      if (y == 0) {
        bf16* orow = qout + (size_t)row * 128 + lr;
#pragma unroll
        for (int j = 0; j < 8; ++j) orow[16 * j] = __float2bfloat16(acc[i][j][r] + bs[j]);
      } else {
        unsigned char* orow = f8dst + (size_t)row * 128 + lr;
#pragma unroll
        for (int j = 0; j < 8; ++j) orow[16 * j] = f_to_fp8(acc[i][j][r] + bs[j]);
      }
    }
}

// ---------------------------------------------------------------------------
// FFN1 (K=128, N=512 via blockIdx.y): bias + relu -> h (fp8 e4m3)
// ---------------------------------------------------------------------------
__global__ __launch_bounds__(512, 4) void k_ffn1(
    const bf16* __restrict__ A, const bf16* __restrict__ W,
    const float* __restrict__ bias, unsigned char* __restrict__ out, int M) {
  __shared__ ushort_t Bs[16384];
  const int tid = threadIdx.x;
  const int lane = tid & 63;
  const int wid = tid >> 6;
  const int row0 = blockIdx.x * 256 + wid * 32;
  const int cbase = blockIdx.y * 128;
  const int lr = lane & 15, kg = lane >> 4;

  int r0 = row0 + lr;      if (r0 > M - 1) r0 = M - 1;
  int r1 = row0 + 16 + lr; if (r1 > M - 1) r1 = M - 1;
  frag a[2][4];
#pragma unroll
  for (int kc = 0; kc < 4; ++kc) {
    a[0][kc] = *(const frag*)(A + (size_t)r0 * 128 + kg * 8 + kc * 32);
    a[1][kc] = *(const frag*)(A + (size_t)r1 * 128 + kg * 8 + kc * 32);
  }
  stage_B(W + (size_t)cbase * 128, 128, Bs, tid);
  __syncthreads();

  f32x4 acc[2][8] = {};
  mfma_step(a, Bs, lr, kg, acc);

  float bs[8];
#pragma unroll
  for (int j = 0; j < 8; ++j) bs[j] = bias[cbase + lr + 16 * j];
#pragma unroll
  for (int i = 0; i < 2; ++i)
#pragma unroll
    for (int r = 0; r < 4; ++r) {
      const int row = row0 + 16 * i + 4 * kg + r;
      if (row >= M) continue;
      unsigned char* orow = out + (size_t)row * 512 + cbase + lr;
#pragma unroll
      for (int j = 0; j < 8; ++j)
        orow[16 * j] = f_to_fp8(fmaxf(acc[i][j][r] + bs[j], 0.f));
    }
}

// ---------------------------------------------------------------------------
// out-proj (K=128) + bias + bf16 residual + LN1 -> bf16
// ---------------------------------------------------------------------------
__global__ __launch_bounds__(512, 4) void k_outproj_ln(
    const bf16* __restrict__ A, const bf16* __restrict__ W,
    const float* __restrict__ bias, const bf16* __restrict__ resid,
    const float* __restrict__ g, const float* __restrict__ b,
    bf16* __restrict__ out, int M) {
  __shared__ ushort_t Bs[16384];
  const int tid = threadIdx.x;
  const int lane = tid & 63;
  const int wid = tid >> 6;
  const int row0 = blockIdx.x * 256 + wid * 32;
  const int lr = lane & 15, kg = lane >> 4;

  int r0 = row0 + lr;      if (r0 > M - 1) r0 = M - 1;
  int r1 = row0 + 16 + lr; if (r1 > M - 1) r1 = M - 1;
  frag a[2][4];
#pragma unroll
  for (int kc = 0; kc < 4; ++kc) {
    a[0][kc] = *(const frag*)(A + (size_t)r0 * 128 + kg * 8 + kc * 32);
    a[1][kc] = *(const frag*)(A + (size_t)r1 * 128 + kg * 8 + kc * 32);
  }
  stage_B(W, 128, Bs, tid);
  __syncthreads();

  f32x4 acc[2][8] = {};
  mfma_step(a, Bs, lr, kg, acc);

  float bs[8], gs[8], bbs[8];
#pragma unroll
  for (int j = 0; j < 8; ++j) {
    const int c = lr + 16 * j;
    bs[j] = bias[c]; gs[j] = g[c]; bbs[j] = b[c];
  }
#pragma unroll
  for (int i = 0; i < 2; ++i)
#pragma unroll
    for (int r = 0; r < 4; ++r) {
      const int row = row0 + 16 * i + 4 * kg + r;
      const int rr = (row > M - 1) ? (M - 1) : row;
      const bf16* rrow = resid + (size_t)rr * 128 + lr;
      float v[8], psum = 0.f, psq = 0.f;
#pragma unroll
      for (int j = 0; j < 8; ++j) {
        v[j] = acc[i][j][r] + bs[j] + __bfloat162float(rrow[16 * j]);
        psum += v[j];
        psq += v[j] * v[j];
      }
#pragma unroll
      for (int off = 1; off < 16; off <<= 1) {
        psum += __shfl_xor(psum, off);
        psq += __shfl_xor(psq, off);
      }
      const float mean = psum * (1.f / 128.f);
      const float var = psq * (1.f / 128.f) - mean * mean;
      const float rstd = rsqrtf(var + EPS);
      if (row < M) {
        bf16* orow = out + (size_t)row * 128 + lr;
#pragma unroll
        for (int j = 0; j < 8; ++j)
          orow[16 * j] = __float2bfloat16((v[j] - mean) * rstd * gs[j] + bbs[j]);
      }
    }
}

// ---------------------------------------------------------------------------
// FFN2 (K=512, 4 k-steps) + bias + residual + LN2 -> fp32 out.
// 8 waves x 32 rows; h read as fp8 (inline exact convert to bf16 frags);
// double-buffered 2x32KB LDS for B via global_load_lds; A ping-pong in regs.
// 2 blocks/CU x 8 waves = 16 waves/CU (was 8).
// ---------------------------------------------------------------------------
__global__ __launch_bounds__(512, 4) void k_ffn2_ln(
    const unsigned char* __restrict__ A,  // h [M][512] fp8 e4m3
    const bf16* __restrict__ W,           // [128][512]
    const float* __restrict__ bias, const bf16* __restrict__ resid,
    const float* __restrict__ g, const float* __restrict__ b,
    float* __restrict__ out, int M) {
  __shared__ ushort_t Bs0[16384];
  __shared__ ushort_t Bs1[16384];
  const int tid = threadIdx.x;
  const int lane = tid & 63;
  const int wid = tid >> 6;
  const int row0 = blockIdx.x * 256 + wid * 32;
  const int lr = lane & 15, kg = lane >> 4;

  int r0 = row0 + lr;      if (r0 > M - 1) r0 = M - 1;
  int r1 = row0 + 16 + lr; if (r1 > M - 1) r1 = M - 1;
  const unsigned char* a0 = A + (size_t)r0 * 512 + kg * 8;  // byte offsets
  const unsigned char* a1 = A + (size_t)r1 * 512 + kg * 8;

  f32x4 acc[2][8] = {};
  frag aC[2][4], aN[2][4];

#define LDA(d, c)                                                      \
  { _Pragma("unroll") for (int kc = 0; kc < 4; ++kc) {                 \
      d[0][kc] = fp8x8_to_bf16frag(*(const uint2*)(a0 + (c) * 128 + kc * 32)); \
      d[1][kc] = fp8x8_to_bf16frag(*(const uint2*)(a1 + (c) * 128 + kc * 32)); } }
#define STAGE(Bsx, c)                                             \
  { _Pragma("unroll") for (int r = 0; r < 4; ++r) {               \
      const int gg = r * 512 + tid, row = gg >> 4, u = gg & 15;   \
      GL_LDS16(W + (size_t)row * 512 + (c) * 128 + (u ^ (row & 15)) * 8, Bsx + gg * 8); } }

  LDA(aC, 0);
  STAGE(Bs0, 0);
  __syncthreads();

  LDA(aN, 1);
  STAGE(Bs1, 1);
  mfma_step(aC, Bs0, lr, kg, acc);
  __syncthreads();

  LDA(aC, 2);
  STAGE(Bs0, 2);
  mfma_step(aN, Bs1, lr, kg, acc);
  __syncthreads();

  LDA(aN, 3);
  STAGE(Bs1, 3);
  mfma_step(aC, Bs0, lr, kg, acc);
  __syncthreads();

  mfma_step(aN, Bs1, lr, kg, acc);
#undef LDA
#undef STAGE

  float bs[8], gs[8], bbs[8];
#pragma unroll
  for (int j = 0; j < 8; ++j) {
    const int c = lr + 16 * j;
    bs[j] = bias[c]; gs[j] = g[c]; bbs[j] = b[c];
  }
#pragma unroll
  for (int i = 0; i < 2; ++i)
#pragma unroll
    for (int r = 0; r < 4; ++r) {
      const int row = row0 + 16 * i + 4 * kg + r;
      const int rr = (row > M - 1) ? (M - 1) : row;
      const bf16* rrow = resid + (size_t)rr * 128 + lr;
      float v[8], psum = 0.f, psq = 0.f;
#pragma unroll
      for (int j = 0; j < 8; ++j) {
        v[j] = acc[i][j][r] + bs[j] + __bfloat162float(rrow[16 * j]);
        psum += v[j];
        psq += v[j] * v[j];
      }
#pragma unroll
      for (int off = 1; off < 16; off <<= 1) {
        psum += __shfl_xor(psum, off);
        psq += __shfl_xor(psq, off);
      }
      const float mean = psum * (1.f / 128.f);
      const float var = psq * (1.f / 128.f) - mean * mean;
      const float rstd = rsqrtf(var + EPS);
      if (row < M) {
        float* orow = out + (size_t)row * 128 + lr;
#pragma unroll
        for (int j = 0; j < 8; ++j)
          orow[16 * j] = (v[j] - mean) * rstd * gs[j] + bbs[j];
      }
    }
}

// ---------------------------------------------------------------------------
// Sampled attention, fp8 K/V, 8B gathers (4 sample rows per instruction),
// HW fp8->f32 converts. 409.6 MB logical gather bytes @ ~6.7 TB/s: roofline.
// ---------------------------------------------------------------------------
__global__ __launch_bounds__(256) void attn_kernel(
    const bf16* __restrict__ qb, const unsigned char* __restrict__ kf8,
    const unsigned char* __restrict__ vf8, const int* __restrict__ samples,
    bf16* __restrict__ attn) {
  const int lane = threadIdx.x & 63;
  const int wid = threadIdx.x >> 6;
  const int tok = blockIdx.x * 4 + wid;
  if (tok >= NTOK) return;
  const int qt = lane >> 4;
  const int lr = lane & 15;

  const float scale = 0.17677669529663687f;  // 1/sqrt(32)
  float q8[8];
  {
    uint4 qu = *(const uint4*)&qb[(size_t)tok * 128 + 8 * lr];
    bfu_unpack(qu.x, q8[0], q8[1]);
    bfu_unpack(qu.y, q8[2], q8[3]);
    bfu_unpack(qu.z, q8[4], q8[5]);
    bfu_unpack(qu.w, q8[6], q8[7]);
#pragma unroll
    for (int d = 0; d < 8; ++d) q8[d] *= scale;
  }

  const int myidx = samples[tok * 16 + lr];
  int kidx[4];
#pragma unroll
  for (int jj = 0; jj < 4; ++jj) kidx[jj] = __shfl(myidx, 4 * jj + qt, 16);

  float s[4];
#pragma unroll
  for (int jj = 0; jj < 4; ++jj) {
    uint2 ku = *(const uint2*)&kf8[(size_t)kidx[jj] * 128 + 8 * lr];
    float4 k0 = fp8x4_to_f4(ku.x), k1 = fp8x4_to_f4(ku.y);
    float p = q8[0] * k0.x + q8[1] * k0.y + q8[2] * k0.z + q8[3] * k0.w +
              q8[4] * k1.x + q8[5] * k1.y + q8[6] * k1.z + q8[7] * k1.w;
    p += __shfl_xor(p, 1);
    p += __shfl_xor(p, 2);
    s[jj] = p;
  }

  float m = fmaxf(fmaxf(s[0], s[1]), fmaxf(s[2], s[3]));
  m = fmaxf(m, __shfl_xor(m, 16));
  m = fmaxf(m, __shfl_xor(m, 32));
  float sum = 0.f;
#pragma unroll
  for (int jj = 0; jj < 4; ++jj) {
    s[jj] = __expf(s[jj] - m);
    sum += s[jj];
  }
  sum += __shfl_xor(sum, 16);
  sum += __shfl_xor(sum, 32);
  const float inv = 1.f / sum;

  float a8[8] = {};
#pragma unroll
  for (int jj = 0; jj < 4; ++jj) {
    uint2 vu = *(const uint2*)&vf8[(size_t)kidx[jj] * 128 + 8 * lr];
    float4 v0 = fp8x4_to_f4(vu.x), v1 = fp8x4_to_f4(vu.y);
    const float wj = s[jj] * inv;
    a8[0] += wj * v0.x; a8[1] += wj * v0.y; a8[2] += wj * v0.z; a8[3] += wj * v0.w;
    a8[4] += wj * v1.x; a8[5] += wj * v1.y; a8[6] += wj * v1.z; a8[7] += wj * v1.w;
  }
#pragma unroll
  for (int d = 0; d < 8; ++d) {
    a8[d] += __shfl_xor(a8[d], 16);
    a8[d] += __shfl_xor(a8[d], 32);
  }

  if (qt == 0) {
    uint4 o;
    o.x = (unsigned)__bfloat16_as_ushort(__float2bfloat16(a8[0])) |
          ((unsigned)__bfloat16_as_ushort(__float2bfloat16(a8[1])) << 16);
    o.y = (unsigned)__bfloat16_as_ushort(__float2bfloat16(a8[2])) |
          ((unsigned)__bfloat16_as_ushort(__float2bfloat16(a8[3])) << 16);
    o.z = (unsigned)__bfloat16_as_ushort(__float2bfloat16(a8[4])) |
          ((unsigned)__bfloat16_as_ushort(__float2bfloat16(a8[5])) << 16);
    o.w = (unsigned)__bfloat16_as_ushort(__float2bfloat16(a8[6])) |
          ((unsigned)__bfloat16_as_ushort(__float2bfloat16(a8[7])) << 16);
    *(uint4*)&attn[(size_t)tok * 128 + 8 * lr] = o;
  }
}

extern "C" void kernel_launch(void* const* d_in, const int* in_sizes, int n_in,
                              void* d_out, int out_size, void* d_ws, size_t ws_size,
                              hipStream_t stream) {
  const float* x      = (const float*)d_in[0];
  const int* samples  = (const int*)d_in[1];
  const float* in_w   = (const float*)d_in[2];
  const float* in_b   = (const float*)d_in[3];
  const float* out_w  = (const float*)d_in[4];
  const float* out_b  = (const float*)d_in[5];
  const float* ffn_w1 = (const float*)d_in[6];
  const float* ffn_b1 = (const float*)d_in[7];
  const float* ffn_w2 = (const float*)d_in[8];
  const float* ffn_b2 = (const float*)d_in[9];
  const float* ln1_g  = (const float*)d_in[10];
  const float* ln1_b  = (const float*)d_in[11];
  const float* ln2_g  = (const float*)d_in[12];
  const float* ln2_b  = (const float*)d_in[13];
  float* out = (float*)d_out;

  // ws layout: xb 0 | qb 25.6M | kf8 51.2M | vf8 64M | attn 76.8M | x1b 102.4M | wb 128M
  // h[N][512] fp8 = 51.2 MB aliases [0..51.2M) (xb/qb dead by FFN1)
  char* ws = (char*)d_ws;
  bf16* xb   = (bf16*)(ws);
  bf16* qb   = (bf16*)(ws + 25600000);
  unsigned char* kf8 = (unsigned char*)(ws + 51200000);
  unsigned char* vf8 = (unsigned char*)(ws + 64000000);
  bf16* attn = (bf16*)(ws + 76800000);
  unsigned char* h = (unsigned char*)(ws);
  bf16* x1b  = (bf16*)(ws + 102400000);
  bf16* wb   = (bf16*)(ws + 128000000);
  bf16* in_wb   = wb;
  bf16* out_wb  = wb + 49152;
  bf16* ffn_w1b = wb + 65536;
  bf16* ffn_w2b = wb + 131072;

  const int M = NTOK;
  dim3 blk512(512);
  const int gm = (M + 255) / 256;  // 391 blocks (8 waves x 32 rows)

  cvt_x_kernel<<<dim3(12500), dim3(256), 0, stream>>>(x, xb);
  cvt_w_kernel<<<dim3(192), dim3(256), 0, stream>>>(in_w, out_w, ffn_w1, ffn_w2, wb);
  // 1) QKV projection -> qb (bf16), kf8/vf8 (fp8)
  k_qkv<<<dim3(gm, 3), blk512, 0, stream>>>(xb, in_wb, in_b, qb, kf8, vf8, M);
  // 2) sampled attention -> attn (bf16)
  attn_kernel<<<dim3((M + 3) / 4), dim3(256), 0, stream>>>(qb, kf8, vf8, samples, attn);
  // 3) out-proj + residual(xb) + LN1 -> x1b
  k_outproj_ln<<<dim3(gm), blk512, 0, stream>>>(attn, out_wb, out_b, xb, ln1_g, ln1_b, x1b, M);
  // 4) FFN1 + relu -> h[N][512] (fp8)
  k_ffn1<<<dim3(gm, 4), blk512, 0, stream>>>(x1b, ffn_w1b, ffn_b1, h, M);
  // 5) FFN2 (fp8 h) + residual(x1b) + LN2 -> out (fp32)
  k_ffn2_ln<<<dim3(gm), blk512, 0, stream>>>(h, ffn_w2b, ffn_b2, x1b, ln2_g, ln2_b, out, M);
}

// Round 15
// 189.748 us; speedup vs baseline: 1.0253x; 1.0253x over previous
//
#include <hip/hip_runtime.h>
#include <hip/hip_bf16.h>
#include <hip/hip_fp8.h>

#define NTOK 100000
#define EPS 1e-5f

using frag  = __attribute__((ext_vector_type(8))) short;  // 8 bf16 (4 VGPR)
using f32x4 = __attribute__((ext_vector_type(4))) float;
typedef __hip_bfloat16 bf16;
typedef unsigned short ushort_t;

__device__ inline float bits2f(unsigned int u) { union { unsigned int i; float f; } x; x.i = u; return x.f; }
__device__ inline void bfu_unpack(unsigned int u, float& lo, float& hi) {
  lo = bits2f(u << 16);
  hi = bits2f(u & 0xffff0000u);
}
__device__ inline short f2bf_s(float x) { bf16 t = __float2bfloat16(x); return *(short*)&t; }

// fp8 e4m3 <-> f32 via gfx950 HW converts (SW fallback guarded)
__device__ inline float4 fp8x4_to_f4(unsigned int u) {
#if __has_builtin(__builtin_amdgcn_cvt_pk_f32_fp8)
  auto lo = __builtin_amdgcn_cvt_pk_f32_fp8(u, false);  // bytes 0,1
  auto hi = __builtin_amdgcn_cvt_pk_f32_fp8(u, true);   // bytes 2,3
  return make_float4(lo[0], lo[1], hi[0], hi[1]);
#else
  __hip_fp8_e4m3 a, b, c, d;
  a.__x = u & 0xff; b.__x = (u >> 8) & 0xff; c.__x = (u >> 16) & 0xff; d.__x = (u >> 24) & 0xff;
  return make_float4((float)a, (float)b, (float)c, (float)d);
#endif
}
__device__ inline unsigned char f_to_fp8(float f) {
#if __has_builtin(__builtin_amdgcn_cvt_pk_fp8_f32)
  return (unsigned char)(__builtin_amdgcn_cvt_pk_fp8_f32(f, f, 0, false) & 0xff);
#else
  __hip_fp8_e4m3 t(f); return t.__x;
#endif
}
// 8 fp8 (uint2) -> bf16 MFMA A-frag; exact re-encode (e4m3 subset of bf16)
__device__ inline frag fp8x8_to_bf16frag(uint2 u) {
  float4 a = fp8x4_to_f4(u.x);
  float4 b = fp8x4_to_f4(u.y);
  frag f;
  f[0] = f2bf_s(a.x); f[1] = f2bf_s(a.y); f[2] = f2bf_s(a.z); f[3] = f2bf_s(a.w);
  f[4] = f2bf_s(b.x); f[5] = f2bf_s(b.y); f[6] = f2bf_s(b.z); f[7] = f2bf_s(b.w);
  return f;
}

// async global->LDS, 16B per lane; zero VGPR staging cost.
#define GL_LDS16(gsrc, ldst)                                                  \
  __builtin_amdgcn_global_load_lds(                                           \
      (const __attribute__((address_space(1))) void*)(gsrc),                  \
      (__attribute__((address_space(3))) void*)(ldst), 16, 0, 0)

// ---------------------------------------------------------------------------
// fused fp32 -> bf16 conversion: blocks [0,12500) convert x, [12500,12692) w
// ---------------------------------------------------------------------------
__global__ __launch_bounds__(256) void cvt_all_kernel(
    const float* __restrict__ x, bf16* __restrict__ xb,
    const float* __restrict__ w0, const float* __restrict__ w1,
    const float* __restrict__ w2, const float* __restrict__ w3,
    bf16* __restrict__ wb) {
  const int b = blockIdx.x;
  if (b < 12500) {
    const int e = (b * 256 + threadIdx.x) * 4;
    float4 v = *(const float4*)&x[e];
    bf16 o[4] = {__float2bfloat16(v.x), __float2bfloat16(v.y),
                 __float2bfloat16(v.z), __float2bfloat16(v.w)};
    *(ulong1*)&xb[e] = *(ulong1*)o;
  } else {
    const int e = ((b - 12500) * 256 + threadIdx.x) * 4;
    const float* src;
    int off;
    if (e < 49152)       { src = w0; off = 0; }
    else if (e < 65536)  { src = w1; off = 49152; }
    else if (e < 131072) { src = w2; off = 65536; }
    else                 { src = w3; off = 131072; }
    float4 v = *(const float4*)&src[e - off];
    bf16 o[4] = {__float2bfloat16(v.x), __float2bfloat16(v.y),
                 __float2bfloat16(v.z), __float2bfloat16(v.w)};
    *(ulong1*)&wb[e] = *(ulong1*)o;
  }
}

// ---------------------------------------------------------------------------
// B staging via global_load_lds, 256-thread form: slot g = r*256+tid
// (row=g>>4, u=g&15), byte offset g*16 -- LINEAR in lane. Swizzle in the
// per-lane GLOBAL address: unit u^(row&15). Frag read: unit (kc*4+kg)^lr
// (measured 0 bank conflicts).
// ---------------------------------------------------------------------------
__device__ __forceinline__ void stage_B(const bf16* __restrict__ Wslab, int KTOT,
                                        ushort_t* Bs, int tid) {
#pragma unroll
  for (int r = 0; r < 8; ++r) {
    const int g = r * 256 + tid, row = g >> 4, u = g & 15;
    GL_LDS16(Wslab + (size_t)row * KTOT + (u ^ (row & 15)) * 8, Bs + g * 8);
  }
}

// 64 MFMAs over one staged 128x128 B chunk with preloaded A frags
__device__ __forceinline__ void mfma_step(const frag (&a)[2][4], ushort_t* Bs,
                                          int lr, int kg, f32x4 (&acc)[2][8]) {
#pragma unroll
  for (int kc = 0; kc < 4; ++kc) {
    const int uoff = ((kc * 4 + kg) ^ lr) * 8;
#pragma unroll
    for (int j = 0; j < 8; ++j) {
      frag b = *(const frag*)&Bs[(lr + 16 * j) * 128 + uoff];
      acc[0][j] = __builtin_amdgcn_mfma_f32_16x16x32_bf16(a[0][kc], b, acc[0][j], 0, 0, 0);
      acc[1][j] = __builtin_amdgcn_mfma_f32_16x16x32_bf16(a[1][kc], b, acc[1][j], 0, 0, 0);
    }
  }
}

// ---------------------------------------------------------------------------
// QKV projection (K=128): 256 threads, 128-row block (782-block grid).
// blockIdx.y 0 -> q (bf16), 1 -> k (fp8), 2 -> v (fp8)
// ---------------------------------------------------------------------------
__global__ __launch_bounds__(256, 4) void k_qkv(
    const bf16* __restrict__ A, const bf16* __restrict__ W,
    const float* __restrict__ bias, bf16* __restrict__ qout,
    unsigned char* __restrict__ kout, unsigned char* __restrict__ vout, int M) {
  __shared__ ushort_t Bs[16384];
  const int tid = threadIdx.x;
  const int lane = tid & 63;
  const int wid = tid >> 6;
  const int row0 = blockIdx.x * 128 + wid * 32;
  const int cbase = blockIdx.y * 128;
  const int lr = lane & 15, kg = lane >> 4;

  int r0 = row0 + lr;      if (r0 > M - 1) r0 = M - 1;
  int r1 = row0 + 16 + lr; if (r1 > M - 1) r1 = M - 1;
  frag a[2][4];
#pragma unroll
  for (int kc = 0; kc < 4; ++kc) {
    a[0][kc] = *(const frag*)(A + (size_t)r0 * 128 + kg * 8 + kc * 32);
    a[1][kc] = *(const frag*)(A + (size_t)r1 * 128 + kg * 8 + kc * 32);
  }
  stage_B(W + (size_t)cbase * 128, 128, Bs, tid);
  __syncthreads();  // drains vmcnt(0): B in LDS, A in regs

  f32x4 acc[2][8] = {};
  mfma_step(a, Bs, lr, kg, acc);

  float bs[8];
#pragma unroll
  for (int j = 0; j < 8; ++j) bs[j] = bias[cbase + lr + 16 * j];
  const int y = blockIdx.y;
  unsigned char* f8dst = (y == 1) ? kout : vout;
#pragma unroll
  for (int i = 0; i < 2; ++i)
#pragma unroll
    for (int r = 0; r < 4; ++r) {
      const int row = row0 + 16 * i + 4 * kg + r;
      if (row >= M) continue;
      if (y == 0) {
        bf16* orow = qout + (size_t)row * 128 + lr;
#pragma unroll
        for (int j = 0; j < 8; ++j) orow[16 * j] = __float2bfloat16(acc[i][j][r] + bs[j]);
      } else {
        unsigned char* orow = f8dst + (size_t)row * 128 + lr;
#pragma unroll
        for (int j = 0; j < 8; ++j) orow[16 * j] = f_to_fp8(acc[i][j][r] + bs[j]);
      }
    }
}

// ---------------------------------------------------------------------------
// FFN1 (K=128, N=512 via blockIdx.y): bias + relu -> h (fp8 e4m3)
// ---------------------------------------------------------------------------
__global__ __launch_bounds__(256, 4) void k_ffn1(
    const bf16* __restrict__ A, const bf16* __restrict__ W,
    const float* __restrict__ bias, unsigned char* __restrict__ out, int M) {
  __shared__ ushort_t Bs[16384];
  const int tid = threadIdx.x;
  const int lane = tid & 63;
  const int wid = tid >> 6;
  const int row0 = blockIdx.x * 128 + wid * 32;
  const int cbase = blockIdx.y * 128;
  const int lr = lane & 15, kg = lane >> 4;

  int r0 = row0 + lr;      if (r0 > M - 1) r0 = M - 1;
  int r1 = row0 + 16 + lr; if (r1 > M - 1) r1 = M - 1;
  frag a[2][4];
#pragma unroll
  for (int kc = 0; kc < 4; ++kc) {
    a[0][kc] = *(const frag*)(A + (size_t)r0 * 128 + kg * 8 + kc * 32);
    a[1][kc] = *(const frag*)(A + (size_t)r1 * 128 + kg * 8 + kc * 32);
  }
  stage_B(W + (size_t)cbase * 128, 128, Bs, tid);
  __syncthreads();

  f32x4 acc[2][8] = {};
  mfma_step(a, Bs, lr, kg, acc);

  float bs[8];
#pragma unroll
  for (int j = 0; j < 8; ++j) bs[j] = bias[cbase + lr + 16 * j];
#pragma unroll
  for (int i = 0; i < 2; ++i)
#pragma unroll
    for (int r = 0; r < 4; ++r) {
      const int row = row0 + 16 * i + 4 * kg + r;
      if (row >= M) continue;
      unsigned char* orow = out + (size_t)row * 512 + cbase + lr;
#pragma unroll
      for (int j = 0; j < 8; ++j)
        orow[16 * j] = f_to_fp8(fmaxf(acc[i][j][r] + bs[j], 0.f));
    }
}

// ---------------------------------------------------------------------------
// out-proj (K=128) + bias + bf16 residual + LN1 -> bf16
// ---------------------------------------------------------------------------
__global__ __launch_bounds__(256, 4) void k_outproj_ln(
    const bf16* __restrict__ A, const bf16* __restrict__ W,
    const float* __restrict__ bias, const bf16* __restrict__ resid,
    const float* __restrict__ g, const float* __restrict__ b,
    bf16* __restrict__ out, int M) {
  __shared__ ushort_t Bs[16384];
  const int tid = threadIdx.x;
  const int lane = tid & 63;
  const int wid = tid >> 6;
  const int row0 = blockIdx.x * 128 + wid * 32;
  const int lr = lane & 15, kg = lane >> 4;

  int r0 = row0 + lr;      if (r0 > M - 1) r0 = M - 1;
  int r1 = row0 + 16 + lr; if (r1 > M - 1) r1 = M - 1;
  frag a[2][4];
#pragma unroll
  for (int kc = 0; kc < 4; ++kc) {
    a[0][kc] = *(const frag*)(A + (size_t)r0 * 128 + kg * 8 + kc * 32);
    a[1][kc] = *(const frag*)(A + (size_t)r1 * 128 + kg * 8 + kc * 32);
  }
  stage_B(W, 128, Bs, tid);
  __syncthreads();

  f32x4 acc[2][8] = {};
  mfma_step(a, Bs, lr, kg, acc);

  float bs[8], gs[8], bbs[8];
#pragma unroll
  for (int j = 0; j < 8; ++j) {
    const int c = lr + 16 * j;
    bs[j] = bias[c]; gs[j] = g[c]; bbs[j] = b[c];
  }
#pragma unroll
  for (int i = 0; i < 2; ++i)
#pragma unroll
    for (int r = 0; r < 4; ++r) {
      const int row = row0 + 16 * i + 4 * kg + r;
      const int rr = (row > M - 1) ? (M - 1) : row;
      const bf16* rrow = resid + (size_t)rr * 128 + lr;
      float v[8], psum = 0.f, psq = 0.f;
#pragma unroll
      for (int j = 0; j < 8; ++j) {
        v[j] = acc[i][j][r] + bs[j] + __bfloat162float(rrow[16 * j]);
        psum += v[j];
        psq += v[j] * v[j];
      }
#pragma unroll
      for (int off = 1; off < 16; off <<= 1) {
        psum += __shfl_xor(psum, off);
        psq += __shfl_xor(psq, off);
      }
      const float mean = psum * (1.f / 128.f);
      const float var = psq * (1.f / 128.f) - mean * mean;
      const float rstd = rsqrtf(var + EPS);
      if (row < M) {
        bf16* orow = out + (size_t)row * 128 + lr;
#pragma unroll
        for (int j = 0; j < 8; ++j)
          orow[16 * j] = __float2bfloat16((v[j] - mean) * rstd * gs[j] + bbs[j]);
      }
    }
}

// ---------------------------------------------------------------------------
// FFN2 (K=512, 4 k-steps) + bias + residual + LN2 -> fp32 out.
// 512 threads = 8 waves x 32 rows (391-block grid: single block-round,
// 16 waves/CU). h read as fp8 (inline exact convert); double-buffered
// 2x32KB LDS for B via global_load_lds; A ping-pong in regs.
// ---------------------------------------------------------------------------
__global__ __launch_bounds__(512, 4) void k_ffn2_ln(
    const unsigned char* __restrict__ A,  // h [M][512] fp8 e4m3
    const bf16* __restrict__ W,           // [128][512]
    const float* __restrict__ bias, const bf16* __restrict__ resid,
    const float* __restrict__ g, const float* __restrict__ b,
    float* __restrict__ out, int M) {
  __shared__ ushort_t Bs0[16384];
  __shared__ ushort_t Bs1[16384];
  const int tid = threadIdx.x;
  const int lane = tid & 63;
  const int wid = tid >> 6;
  const int row0 = blockIdx.x * 256 + wid * 32;
  const int lr = lane & 15, kg = lane >> 4;

  int r0 = row0 + lr;      if (r0 > M - 1) r0 = M - 1;
  int r1 = row0 + 16 + lr; if (r1 > M - 1) r1 = M - 1;
  const unsigned char* a0 = A + (size_t)r0 * 512 + kg * 8;  // byte offsets
  const unsigned char* a1 = A + (size_t)r1 * 512 + kg * 8;

  f32x4 acc[2][8] = {};
  frag aC[2][4], aN[2][4];

#define LDA(d, c)                                                      \
  { _Pragma("unroll") for (int kc = 0; kc < 4; ++kc) {                 \
      d[0][kc] = fp8x8_to_bf16frag(*(const uint2*)(a0 + (c) * 128 + kc * 32)); \
      d[1][kc] = fp8x8_to_bf16frag(*(const uint2*)(a1 + (c) * 128 + kc * 32)); } }
#define STAGE(Bsx, c)                                             \
  { _Pragma("unroll") for (int r = 0; r < 4; ++r) {               \
      const int gg = r * 512 + tid, row = gg >> 4, u = gg & 15;   \
      GL_LDS16(W + (size_t)row * 512 + (c) * 128 + (u ^ (row & 15)) * 8, Bsx + gg * 8); } }

  LDA(aC, 0);
  STAGE(Bs0, 0);
  __syncthreads();

  LDA(aN, 1);
  STAGE(Bs1, 1);
  mfma_step(aC, Bs0, lr, kg, acc);
  __syncthreads();

  LDA(aC, 2);
  STAGE(Bs0, 2);
  mfma_step(aN, Bs1, lr, kg, acc);
  __syncthreads();

  LDA(aN, 3);
  STAGE(Bs1, 3);
  mfma_step(aC, Bs0, lr, kg, acc);
  __syncthreads();

  mfma_step(aN, Bs1, lr, kg, acc);
#undef LDA
#undef STAGE

  float bs[8], gs[8], bbs[8];
#pragma unroll
  for (int j = 0; j < 8; ++j) {
    const int c = lr + 16 * j;
    bs[j] = bias[c]; gs[j] = g[c]; bbs[j] = b[c];
  }
#pragma unroll
  for (int i = 0; i < 2; ++i)
#pragma unroll
    for (int r = 0; r < 4; ++r) {
      const int row = row0 + 16 * i + 4 * kg + r;
      const int rr = (row > M - 1) ? (M - 1) : row;
      const bf16* rrow = resid + (size_t)rr * 128 + lr;
      float v[8], psum = 0.f, psq = 0.f;
#pragma unroll
      for (int j = 0; j < 8; ++j) {
        v[j] = acc[i][j][r] + bs[j] + __bfloat162float(rrow[16 * j]);
        psum += v[j];
        psq += v[j] * v[j];
      }
#pragma unroll
      for (int off = 1; off < 16; off <<= 1) {
        psum += __shfl_xor(psum, off);
        psq += __shfl_xor(psq, off);
      }
      const float mean = psum * (1.f / 128.f);
      const float var = psq * (1.f / 128.f) - mean * mean;
      const float rstd = rsqrtf(var + EPS);
      if (row < M) {
        float* orow = out + (size_t)row * 128 + lr;
#pragma unroll
        for (int j = 0; j < 8; ++j)
          orow[16 * j] = (v[j] - mean) * rstd * gs[j] + bbs[j];
      }
    }
}

// ---------------------------------------------------------------------------
// Sampled attention, fp8 K/V, 8B gathers (4 sample rows per instruction),
// HW fp8->f32 converts. 409.6 MB logical gather bytes @ ~6.7 TB/s: roofline.
// ---------------------------------------------------------------------------
__global__ __launch_bounds__(256) void attn_kernel(
    const bf16* __restrict__ qb, const unsigned char* __restrict__ kf8,
    const unsigned char* __restrict__ vf8, const int* __restrict__ samples,
    bf16* __restrict__ attn) {
  const int lane = threadIdx.x & 63;
  const int wid = threadIdx.x >> 6;
  const int tok = blockIdx.x * 4 + wid;
  if (tok >= NTOK) return;
  const int qt = lane >> 4;
  const int lr = lane & 15;

  const float scale = 0.17677669529663687f;  // 1/sqrt(32)
  float q8[8];
  {
    uint4 qu = *(const uint4*)&qb[(size_t)tok * 128 + 8 * lr];
    bfu_unpack(qu.x, q8[0], q8[1]);
    bfu_unpack(qu.y, q8[2], q8[3]);
    bfu_unpack(qu.z, q8[4], q8[5]);
    bfu_unpack(qu.w, q8[6], q8[7]);
#pragma unroll
    for (int d = 0; d < 8; ++d) q8[d] *= scale;
  }

  const int myidx = samples[tok * 16 + lr];
  int kidx[4];
#pragma unroll
  for (int jj = 0; jj < 4; ++jj) kidx[jj] = __shfl(myidx, 4 * jj + qt, 16);

  float s[4];
#pragma unroll
  for (int jj = 0; jj < 4; ++jj) {
    uint2 ku = *(const uint2*)&kf8[(size_t)kidx[jj] * 128 + 8 * lr];
    float4 k0 = fp8x4_to_f4(ku.x), k1 = fp8x4_to_f4(ku.y);
    float p = q8[0] * k0.x + q8[1] * k0.y + q8[2] * k0.z + q8[3] * k0.w +
              q8[4] * k1.x + q8[5] * k1.y + q8[6] * k1.z + q8[7] * k1.w;
    p += __shfl_xor(p, 1);
    p += __shfl_xor(p, 2);
    s[jj] = p;
  }

  float m = fmaxf(fmaxf(s[0], s[1]), fmaxf(s[2], s[3]));
  m = fmaxf(m, __shfl_xor(m, 16));
  m = fmaxf(m, __shfl_xor(m, 32));
  float sum = 0.f;
#pragma unroll
  for (int jj = 0; jj < 4; ++jj) {
    s[jj] = __expf(s[jj] - m);
    sum += s[jj];
  }
  sum += __shfl_xor(sum, 16);
  sum += __shfl_xor(sum, 32);
  const float inv = 1.f / sum;

  float a8[8] = {};
#pragma unroll
  for (int jj = 0; jj < 4; ++jj) {
    uint2 vu = *(const uint2*)&vf8[(size_t)kidx[jj] * 128 + 8 * lr];
    float4 v0 = fp8x4_to_f4(vu.x), v1 = fp8x4_to_f4(vu.y);
    const float wj = s[jj] * inv;
    a8[0] += wj * v0.x; a8[1] += wj * v0.y; a8[2] += wj * v0.z; a8[3] += wj * v0.w;
    a8[4] += wj * v1.x; a8[5] += wj * v1.y; a8[6] += wj * v1.z; a8[7] += wj * v1.w;
  }
#pragma unroll
  for (int d = 0; d < 8; ++d) {
    a8[d] += __shfl_xor(a8[d], 16);
    a8[d] += __shfl_xor(a8[d], 32);
  }

  if (qt == 0) {
    uint4 o;
    o.x = (unsigned)__bfloat16_as_ushort(__float2bfloat16(a8[0])) |
          ((unsigned)__bfloat16_as_ushort(__float2bfloat16(a8[1])) << 16);
    o.y = (unsigned)__bfloat16_as_ushort(__float2bfloat16(a8[2])) |
          ((unsigned)__bfloat16_as_ushort(__float2bfloat16(a8[3])) << 16);
    o.z = (unsigned)__bfloat16_as_ushort(__float2bfloat16(a8[4])) |
          ((unsigned)__bfloat16_as_ushort(__float2bfloat16(a8[5])) << 16);
    o.w = (unsigned)__bfloat16_as_ushort(__float2bfloat16(a8[6])) |
          ((unsigned)__bfloat16_as_ushort(__float2bfloat16(a8[7])) << 16);
    *(uint4*)&attn[(size_t)tok * 128 + 8 * lr] = o;
  }
}

extern "C" void kernel_launch(void* const* d_in, const int* in_sizes, int n_in,
                              void* d_out, int out_size, void* d_ws, size_t ws_size,
                              hipStream_t stream) {
  const float* x      = (const float*)d_in[0];
  const int* samples  = (const int*)d_in[1];
  const float* in_w   = (const float*)d_in[2];
  const float* in_b   = (const float*)d_in[3];
  const float* out_w  = (const float*)d_in[4];
  const float* out_b  = (const float*)d_in[5];
  const float* ffn_w1 = (const float*)d_in[6];
  const float* ffn_b1 = (const float*)d_in[7];
  const float* ffn_w2 = (const float*)d_in[8];
  const float* ffn_b2 = (const float*)d_in[9];
  const float* ln1_g  = (const float*)d_in[10];
  const float* ln1_b  = (const float*)d_in[11];
  const float* ln2_g  = (const float*)d_in[12];
  const float* ln2_b  = (const float*)d_in[13];
  float* out = (float*)d_out;

  // ws layout: xb 0 | qb 25.6M | kf8 51.2M | vf8 64M | attn 76.8M | x1b 102.4M | wb 128M
  // h[N][512] fp8 = 51.2 MB aliases [0..51.2M) (xb/qb dead by FFN1)
  char* ws = (char*)d_ws;
  bf16* xb   = (bf16*)(ws);
  bf16* qb   = (bf16*)(ws + 25600000);
  unsigned char* kf8 = (unsigned char*)(ws + 51200000);
  unsigned char* vf8 = (unsigned char*)(ws + 64000000);
  bf16* attn = (bf16*)(ws + 76800000);
  unsigned char* h = (unsigned char*)(ws);
  bf16* x1b  = (bf16*)(ws + 102400000);
  bf16* wb   = (bf16*)(ws + 128000000);
  bf16* in_wb   = wb;
  bf16* out_wb  = wb + 49152;
  bf16* ffn_w1b = wb + 65536;
  bf16* ffn_w2b = wb + 131072;

  const int M = NTOK;
  dim3 blk(256);
  const int gm = (M + 127) / 128;   // 782 blocks (4 waves x 32 rows)
  const int gm2 = (M + 255) / 256;  // 391 blocks (8 waves x 32 rows, ffn2)

  // 0) fused conversions (x -> bf16, weights -> bf16) in one dispatch
  cvt_all_kernel<<<dim3(12692), blk, 0, stream>>>(x, xb, in_w, out_w, ffn_w1, ffn_w2, wb);
  // 1) QKV projection -> qb (bf16), kf8/vf8 (fp8)
  k_qkv<<<dim3(gm, 3), blk, 0, stream>>>(xb, in_wb, in_b, qb, kf8, vf8, M);
  // 2) sampled attention -> attn (bf16)
  attn_kernel<<<dim3((M + 3) / 4), blk, 0, stream>>>(qb, kf8, vf8, samples, attn);
  // 3) out-proj + residual(xb) + LN1 -> x1b
  k_outproj_ln<<<dim3(gm), blk, 0, stream>>>(attn, out_wb, out_b, xb, ln1_g, ln1_b, x1b, M);
  // 4) FFN1 + relu -> h[N][512] (fp8)
  k_ffn1<<<dim3(gm, 4), blk, 0, stream>>>(x1b, ffn_w1b, ffn_b1, h, M);
  // 5) FFN2 (fp8 h, 512-thread blocks) + residual(x1b) + LN2 -> out (fp32)
  k_ffn2_ln<<<dim3(gm2), dim3(512), 0, stream>>>(h, ffn_w2b, ffn_b2, x1b, ln2_g, ln2_b, out, M);
}